// Round 17
// baseline (76.628 us; speedup 1.0000x reference)
//
#include <hip/hip_runtime.h>
#include <hip/hip_bf16.h>

typedef __attribute__((ext_vector_type(8))) short bf16x8;
typedef __attribute__((ext_vector_type(4))) short bf16x4;
typedef __attribute__((ext_vector_type(4))) float f32x4;

#define NO 256

static __device__ __forceinline__ void gld16(const void* g, void* l) {
    __builtin_amdgcn_global_load_lds(
        (const __attribute__((address_space(1))) void*)g,
        (__attribute__((address_space(3))) void*)l, 16, 0, 0);
}

// prep: wrt only. Layout, groups of 8 shorts: [s=tap*4+ic][kw2][mw][mf][klo][kcol][e8]
__global__ void prep_kernel(const float* __restrict__ w2, __hip_bfloat16* __restrict__ wrt) {
    int idx = blockIdx.x * 256 + threadIdx.x;   // [0, 73728)
    int kcol = idx & 15;
    int klo = (idx >> 4) & 3;
    int mf = (idx >> 6) & 3;
    int mw = (idx >> 8) & 3;
    int kw2 = (idx >> 10) & 1;
    int s = idx >> 11;
    int tap = s >> 2;
    int ic = s & 3;
    int o = mw * 64 + mf * 16 + kcol;
    int ch = kw2 * 128 + ic * 32 + klo * 8;
    const float* src = w2 + (size_t)o * 2304 + (size_t)ch * 9 + tap;
    union { bf16x8 v; __hip_bfloat16 e[8]; } u;
#pragma unroll
    for (int e = 0; e < 8; ++e) u.e[e] = __float2bfloat16(src[e * 9]);
    *(bf16x8*)((short*)wrt + (size_t)idx * 8) = u.v;
}

#define MM(A_, B_, mf_, nf_) \
    acc[mf_][nf_] = __builtin_amdgcn_mfma_f32_16x16x32_bf16(A_, B_, acc[mf_][nf_], 0, 0, 0);

#define CL_H1(A0, A1, A2, A3, B0, B1, B2, B3)                           \
    __builtin_amdgcn_s_setprio(1);                                      \
    MM(A0, B0, 0, 0) MM(A1, B0, 1, 0) MM(A2, B0, 2, 0) MM(A3, B0, 3, 0) \
    MM(A0, B1, 0, 1) MM(A1, B1, 1, 1) MM(A2, B1, 2, 1) MM(A3, B1, 3, 1) \
    MM(A0, B2, 0, 2) MM(A1, B2, 1, 2) MM(A2, B2, 2, 2) MM(A3, B2, 3, 2) \
    MM(A0, B3, 0, 3) MM(A1, B3, 1, 3) MM(A2, B3, 2, 3) MM(A3, B3, 3, 3) \
    __builtin_amdgcn_s_setprio(0);
#define CL_H2(A0, A1, A2, A3, B4, B5, B6)                               \
    __builtin_amdgcn_s_setprio(1);                                      \
    MM(A0, B4, 0, 4) MM(A1, B4, 1, 4) MM(A2, B4, 2, 4) MM(A3, B4, 3, 4) \
    MM(A0, B5, 0, 5) MM(A1, B5, 1, 5) MM(A2, B5, 2, 5) MM(A3, B5, 3, 5) \
    MM(A0, B6, 0, 6) MM(A1, B6, 1, 6) MM(A2, B6, 2, 6) MM(A3, B6, 3, 6) \
    __builtin_amdgcn_s_setprio(0);

// Half-slab layout: position sp (0..179) x 128 ch -> 16 chunks of 16B.
// Chunk w=(ch&127)>>3 stored at sp*256 + ((w ^ key(sp))<<4), key=(q+4r)&7.
// Reader (icc,klo): w=icc*4+klo; addr = (u ^ ((kk&7)<<4)) ^ (icc<<6) with
// u = sp*256 + (klo<<4)  [bit-exact: bits4-5 klo^key&3, bit6 (icc&1)^(key>>2),
// bit7 icc>>1 == sp*256 | ((w^key)<<4)].  Banks: sp*256 ≡ 0 (mod 32 banks) so
// 16 kcol-lanes spread over 8 slots via key -> 2-way (free, m136).
#define LOADB(D0, D1, D2, D3, D4, D5, D6, XO)                                  \
    D0 = *(const bf16x8*)(Xs + ((u[0] ^ ((kk[0] & 7u) << 4)) ^ (XO)));         \
    D1 = *(const bf16x8*)(Xs + ((u[1] ^ ((kk[1] & 7u) << 4)) ^ (XO)));         \
    D2 = *(const bf16x8*)(Xs + ((u[2] ^ ((kk[2] & 7u) << 4)) ^ (XO)));         \
    D3 = *(const bf16x8*)(Xs + ((u[3] ^ ((kk[3] & 7u) << 4)) ^ (XO)));         \
    D4 = *(const bf16x8*)(Xs + ((u[4] ^ ((kk[4] & 7u) << 4)) ^ (XO)));         \
    D5 = *(const bf16x8*)(Xs + ((u[5] ^ ((kk[5] & 7u) << 4)) ^ (XO)));         \
    D6 = *(const bf16x8*)(Xs + ((u[6] ^ ((kk[6] & 7u) << 4)) ^ (XO)));

// Pipelined phase (r14-verified structure): H1 -> {vmcnt(4), A(s+1) ds_read,
// DMA stage(s+3), LOADB B(s+1)} -> H2. All loads consumed one phase after issue.
#define PHASE_E(BUFOFF, XON)                                                  \
    {                                                                         \
        CL_H1(aA0, aA1, aA2, aA3, bA0, bA1, bA2, bA3)                         \
        asm volatile("s_waitcnt vmcnt(4)" ::: "memory");                      \
        aB0 = *(const bf16x8*)(AbR + (BUFOFF));                               \
        aB1 = *(const bf16x8*)(AbR + (BUFOFF) + 1024);                        \
        aB2 = *(const bf16x8*)(AbR + (BUFOFF) + 2048);                        \
        aB3 = *(const bf16x8*)(AbR + (BUFOFF) + 3072);                        \
        gld16(pG, AbW + (BUFOFF));                                            \
        gld16(pG + 1024, AbW + (BUFOFF) + 1024);                              \
        gld16(pG + 2048, AbW + (BUFOFF) + 2048);                              \
        gld16(pG + 3072, AbW + (BUFOFF) + 3072);                              \
        pG += 32768;                                                          \
        LOADB(bB0, bB1, bB2, bB3, bB4, bB5, bB6, XON)                         \
        __builtin_amdgcn_sched_barrier(0);                                    \
        CL_H2(aA0, aA1, aA2, aA3, bA4, bA5, bA6)                              \
    }
#define PHASE_O(BUFOFF, XON)                                                  \
    {                                                                         \
        CL_H1(aB0, aB1, aB2, aB3, bB0, bB1, bB2, bB3)                         \
        asm volatile("s_waitcnt vmcnt(4)" ::: "memory");                      \
        aA0 = *(const bf16x8*)(AbR + (BUFOFF));                               \
        aA1 = *(const bf16x8*)(AbR + (BUFOFF) + 1024);                        \
        aA2 = *(const bf16x8*)(AbR + (BUFOFF) + 2048);                        \
        aA3 = *(const bf16x8*)(AbR + (BUFOFF) + 3072);                        \
        gld16(pG, AbW + (BUFOFF));                                            \
        gld16(pG + 1024, AbW + (BUFOFF) + 1024);                              \
        gld16(pG + 2048, AbW + (BUFOFF) + 2048);                              \
        gld16(pG + 3072, AbW + (BUFOFF) + 3072);                              \
        pG += 32768;                                                          \
        LOADB(bA0, bA1, bA2, bA3, bA4, bA5, bA6, XON)                         \
        __builtin_amdgcn_sched_barrier(0);                                    \
        CL_H2(aB0, aB1, aB2, aB3, bB4, bB5, bB6)                              \
    }

// kw2-split implicit-GEMM conv: 448 blocks x 256 thr (4 waves = mw). Block
// (b, nt, kw2) computes the partial over its 128-ch half and unsafeAtomicAdds
// h[2o+kw2]*acc into zeroed out (2 adds/elem -> exactly deterministic).
// 78 KB LDS -> 2 independent blocks/CU -> 2 independent streams/SIMD.
__global__ __launch_bounds__(256, 2) void conv_kernel(
    const float* __restrict__ x, const __hip_bfloat16* __restrict__ wrt,
    const float* __restrict__ xg, const float* __restrict__ w1,
    const float* __restrict__ b1, float* __restrict__ out) {
    __shared__ __align__(16) char SMEM[79872];
    char* Xs = SMEM;                               // 46080: half-channel x-slab
    char* Ab = SMEM + 46080;                       // 32768: A DMA ring (4 waves)
    float* hsm = (float*)(SMEM + 78848);           // 1024: h[2o+kw2] for o=0..255
    const int bid = blockIdx.x;
    const int v = (bid & 7) * 56 + (bid >> 3);     // bijective XCD swizzle (448 % 8 == 0)
    const int kw2 = v & 1;
    const int pair = v >> 1;                       // 0..223
    const int b = pair / 7;
    const int nt = pair - b * 7;
    const int tid = threadIdx.x;
    const int lane = tid & 63;
    const int mw = tid >> 6;                       // wave id 0..3
    const int kcol = lane & 15;
    const int klo = lane >> 4;

    const char* wrtc = (const char*)wrt;
    char* AbW = Ab + mw * 8192;
    const char* AbR = Ab + mw * 8192 + lane * 16;
    const char* pG = wrtc + (kw2 * 4 + mw) * 4096 + lane * 16;

    // stage A steps 0 -> buf0, 1 -> buf1 (drained by prologue __syncthreads)
    gld16(pG, AbW);
    gld16(pG + 1024, AbW + 1024);
    gld16(pG + 2048, AbW + 2048);
    gld16(pG + 3072, AbW + 3072);
    pG += 32768;
    gld16(pG, AbW + 4096);
    gld16(pG + 1024, AbW + 4096 + 1024);
    gld16(pG + 2048, AbW + 4096 + 2048);
    gld16(pG + 3072, AbW + 4096 + 3072);
    pG += 32768;                                   // next staged step = 2

    // h for this half: hsm[o] = sigmoid(xg[b].w1[2o+kw2] + b1[2o+kw2])
    {
        int j = 2 * tid + kw2;
        float s = b1[j];
        const float* g = xg + b * 16;
        const float* w = w1 + j * 16;
#pragma unroll
        for (int c = 0; c < 16; ++c) s += g[c] * w[c];
        hsm[tid] = 1.0f / (1.0f + expf(-s));
    }

    // ---- half-slab staging from x (fp32 NCHW): quad-channel b64 swizzled writes.
    {
        const bf16x8 z = (bf16x8){0, 0, 0, 0, 0, 0, 0, 0};
        for (int e = tid; e < 6 * 2 * 16; e += 256) {        // pad cols 0/29
            int w = e & 15;
            int t2 = e >> 4;
            int row = t2 >> 1;
            int col = (t2 & 1) ? 29 : 0;
            *(bf16x8*)(Xs + (row * 30 + col) * 256 + w * 16) = z;
        }
        if (nt == 0) {                                        // pad top row
            for (int e = tid; e < 30 * 16; e += 256)
                *(bf16x8*)(Xs + (e >> 4) * 256 + (e & 15) * 16) = z;
        }
        if (nt == 6) {                                        // pad bottom row
            for (int e = tid; e < 30 * 16; e += 256)
                *(bf16x8*)(Xs + (150 + (e >> 4)) * 256 + (e & 15) * 16) = z;
        }
        const int p0 = nt * 4 - 1;
        const float* xb = x + (size_t)b * 256 * 784 + (size_t)kw2 * 128 * 784;
        for (int c = tid; c < 1344; c += 256) {               // 6 rows x 32 quads x 7 c4
            int c4 = c % 7;
            int t2 = c / 7;
            int chq = t2 & 31;                                 // quad within the 128-half
            int row = t2 >> 5;
            int p = p0 + row;
            if (p >= 0 && p < 28) {
                const float* s0 = xb + ((size_t)(chq * 4) * 28 + p) * 28 + 4 * c4;
                f32x4 v0 = *(const f32x4*)(s0);
                f32x4 v1 = *(const f32x4*)(s0 + 784);
                f32x4 v2 = *(const f32x4*)(s0 + 1568);
                f32x4 v3 = *(const f32x4*)(s0 + 2352);
                int w = chq >> 1;                              // chunk 0..15
                int qoff = (chq & 1) * 8;
                int spb = row * 30 + 4 * c4 + 1;
#pragma unroll
                for (int k = 0; k < 4; ++k) {
                    int key = (4 * c4 + 1 + k + 4 * row) & 7;
                    union { bf16x4 vv; __hip_bfloat16 e[4]; } pk;
                    pk.e[0] = __float2bfloat16(v0[k]);
                    pk.e[1] = __float2bfloat16(v1[k]);
                    pk.e[2] = __float2bfloat16(v2[k]);
                    pk.e[3] = __float2bfloat16(v3[k]);
                    *(bf16x4*)(Xs + (spb + k) * 256 + (((w ^ key) << 4) | qoff)) = pk.vv;
                }
            }
        }
    }
    __syncthreads();   // drains: A steps 0/1 DMA landed, Xs+hsm ready

    unsigned u[7], kk[7];
#pragma unroll
    for (int nf = 0; nf < 7; ++nf) {
        int n = nf * 16 + kcol;
        int r0 = n / 28;
        int q0 = n - r0 * 28;
        u[nf] = (unsigned)((r0 * 30 + q0) * 256 + (klo << 4));
        kk[nf] = (unsigned)(q0 + 4 * r0);
    }
    const unsigned xo0 = 0u << 6;
    const unsigned xo1 = 1u << 6;
    const unsigned xo2 = 2u << 6;
    const unsigned xo3 = 3u << 6;

    f32x4 acc[4][7];
#pragma unroll
    for (int mf = 0; mf < 4; ++mf)
#pragma unroll
        for (int nf = 0; nf < 7; ++nf) acc[mf][nf] = (f32x4){0.f, 0.f, 0.f, 0.f};

    bf16x8 aA0, aA1, aA2, aA3, aB0, aB1, aB2, aB3;
    bf16x8 bA0, bA1, bA2, bA3, bA4, bA5, bA6;
    bf16x8 bB0, bB1, bB2, bB3, bB4, bB5, bB6;

    // prologue: A(0) from buf0; re-arm buf0 with stage(2); B(0)
    aA0 = *(const bf16x8*)(AbR);
    aA1 = *(const bf16x8*)(AbR + 1024);
    aA2 = *(const bf16x8*)(AbR + 2048);
    aA3 = *(const bf16x8*)(AbR + 3072);
    gld16(pG, AbW);
    gld16(pG + 1024, AbW + 1024);
    gld16(pG + 2048, AbW + 2048);
    gld16(pG + 3072, AbW + 3072);
    pG += 32768;                                   // next staged step = 3
    LOADB(bA0, bA1, bA2, bA3, bA4, bA5, bA6, xo0)

    for (int tap = 0; tap < 9; ++tap) {
        PHASE_E(4096, xo1)
        PHASE_O(0, xo2)
        PHASE_E(4096, xo3)
        if (tap < 8) {
            const int cross = (tap == 2 || tap == 5);
            const unsigned da = cross ? 28u * 256u : 256u;
            const unsigned dk = cross ? 2u : 1u;
#pragma unroll
            for (int nf = 0; nf < 7; ++nf) { u[nf] += da; kk[nf] += dk; }
        }
        PHASE_O(0, xo0)
    }
    // tail DMA stages read dead bytes past wrt (within ws) -- never consumed.

    // ---- epilogue: no cross-wave exchange; deterministic 2-way atomic combine.
#pragma unroll
    for (int mf = 0; mf < 4; ++mf) {
#pragma unroll
        for (int rr = 0; rr < 4; ++rr) {
            int o = mw * 64 + mf * 16 + klo * 4 + rr;
            float hv = hsm[o];
            float* ob = out + ((size_t)b * NO + o) * 784 + nt * 112 + kcol;
#pragma unroll
            for (int nf = 0; nf < 7; ++nf) {
                unsafeAtomicAdd(ob + nf * 16, hv * acc[mf][nf][rr]);
            }
        }
    }
}

extern "C" void kernel_launch(void* const* d_in, const int* in_sizes, int n_in,
                              void* d_out, int out_size, void* d_ws, size_t ws_size,
                              hipStream_t stream) {
    const float* x = (const float*)d_in[0];
    const float* xg = (const float*)d_in[1];
    const float* w1 = (const float*)d_in[2];
    const float* b1 = (const float*)d_in[3];
    const float* w2 = (const float*)d_in[4];
    float* out = (float*)d_out;

    char* ws = (char*)d_ws;
    __hip_bfloat16* wrt = (__hip_bfloat16*)ws;   // 1,179,648 B (+ tail-overrun slack)

    prep_kernel<<<288, 256, 0, stream>>>(w2, wrt);
    hipMemsetAsync(out, 0, (size_t)out_size * sizeof(float), stream);
    conv_kernel<<<448, 256, 0, stream>>>(x, wrt, xg, w1, b1, out);
}

// Round 18
// 42.066 us; speedup vs baseline: 1.8216x; 1.8216x over previous
//
#include <hip/hip_runtime.h>
#include <hip/hip_bf16.h>

typedef __attribute__((ext_vector_type(8))) short bf16x8;
typedef __attribute__((ext_vector_type(4))) short bf16x4;
typedef __attribute__((ext_vector_type(4))) float f32x4;

#define NO 256

// prep: wrt only. Layout, groups of 8 shorts: [s=tap*4+ic][kw2][mw][mf][klo][kcol][e8]
__global__ void prep_kernel(const float* __restrict__ w2, __hip_bfloat16* __restrict__ wrt) {
    int idx = blockIdx.x * 256 + threadIdx.x;   // [0, 73728)
    int kcol = idx & 15;
    int klo = (idx >> 4) & 3;
    int mf = (idx >> 6) & 3;
    int mw = (idx >> 8) & 3;
    int kw2 = (idx >> 10) & 1;
    int s = idx >> 11;
    int tap = s >> 2;
    int ic = s & 3;
    int o = mw * 64 + mf * 16 + kcol;
    int ch = kw2 * 128 + ic * 32 + klo * 8;
    const float* src = w2 + (size_t)o * 2304 + (size_t)ch * 9 + tap;
    union { bf16x8 v; __hip_bfloat16 e[8]; } u;
#pragma unroll
    for (int e = 0; e < 8; ++e) u.e[e] = __float2bfloat16(src[e * 9]);
    *(bf16x8*)((short*)wrt + (size_t)idx * 8) = u.v;
}

#define MM(A_, B_, mf_, nf_) \
    acc[mf_][nf_] = __builtin_amdgcn_mfma_f32_16x16x32_bf16(A_, B_, acc[mf_][nf_], 0, 0, 0);

#define CL_H1(A0, A1, A2, A3, B0, B1, B2, B3)                           \
    __builtin_amdgcn_s_setprio(1);                                      \
    MM(A0, B0, 0, 0) MM(A1, B0, 1, 0) MM(A2, B0, 2, 0) MM(A3, B0, 3, 0) \
    MM(A0, B1, 0, 1) MM(A1, B1, 1, 1) MM(A2, B1, 2, 1) MM(A3, B1, 3, 1) \
    MM(A0, B2, 0, 2) MM(A1, B2, 1, 2) MM(A2, B2, 2, 2) MM(A3, B2, 3, 2) \
    MM(A0, B3, 0, 3) MM(A1, B3, 1, 3) MM(A2, B3, 2, 3) MM(A3, B3, 3, 3) \
    __builtin_amdgcn_s_setprio(0);
#define CL_H2(A0, A1, A2, A3, B4, B5, B6)                               \
    __builtin_amdgcn_s_setprio(1);                                      \
    MM(A0, B4, 0, 4) MM(A1, B4, 1, 4) MM(A2, B4, 2, 4) MM(A3, B4, 3, 4) \
    MM(A0, B5, 0, 5) MM(A1, B5, 1, 5) MM(A2, B5, 2, 5) MM(A3, B5, 3, 5) \
    MM(A0, B6, 0, 6) MM(A1, B6, 1, 6) MM(A2, B6, 2, 6) MM(A3, B6, 3, 6) \
    __builtin_amdgcn_s_setprio(0);

#define LOADB(D0, D1, D2, D3, D4, D5, D6, XO)                                  \
    D0 = *(const bf16x8*)(Xs + ((u[0] ^ ((kk[0] & 7u) << 4)) ^ (XO)));         \
    D1 = *(const bf16x8*)(Xs + ((u[1] ^ ((kk[1] & 7u) << 4)) ^ (XO)));         \
    D2 = *(const bf16x8*)(Xs + ((u[2] ^ ((kk[2] & 7u) << 4)) ^ (XO)));         \
    D3 = *(const bf16x8*)(Xs + ((u[3] ^ ((kk[3] & 7u) << 4)) ^ (XO)));         \
    D4 = *(const bf16x8*)(Xs + ((u[4] ^ ((kk[4] & 7u) << 4)) ^ (XO)));         \
    D5 = *(const bf16x8*)(Xs + ((u[5] ^ ((kk[5] & 7u) << 4)) ^ (XO)));         \
    D6 = *(const bf16x8*)(Xs + ((u[6] ^ ((kk[6] & 7u) << 4)) ^ (XO)));

// A-fragment register loads for step s+2: 4 coalesced 1KB global loads (wrt is
// L2-resident). Issued at END of phase s (regs just freed by H2); the compiler's
// vmcnt wait lands before H1 of phase s+2 -- a full phase (~2000 cyc) of cover.
#define GLOADA(S0, S1, S2, S3)                   \
    S0 = *(const bf16x8*)(pA);                   \
    S1 = *(const bf16x8*)(pA + 1024);            \
    S2 = *(const bf16x8*)(pA + 2048);            \
    S3 = *(const bf16x8*)(pA + 3072);            \
    pA += 32768;

// Phase (step s): H1(16 MFMA) -> [pin] LOADB B(s+1) [pin] -> H2(12 MFMA) ->
// [pin] GLOADA A(s+2) [pin]. Every load consumed >= 1 phase after issue; no
// LDS traffic for A at all (the pipe co-binding with MFMA carries only B).
#define PHASE_E(XON)                                                          \
    {                                                                         \
        CL_H1(aE0, aE1, aE2, aE3, bc0, bc1, bc2, bc3)                         \
        __builtin_amdgcn_sched_barrier(0);                                    \
        LOADB(bn0, bn1, bn2, bn3, bn4, bn5, bn6, XON)                         \
        __builtin_amdgcn_sched_barrier(0);                                    \
        CL_H2(aE0, aE1, aE2, aE3, bc4, bc5, bc6)                              \
        __builtin_amdgcn_sched_barrier(0);                                    \
        GLOADA(aE0, aE1, aE2, aE3)                                            \
        __builtin_amdgcn_sched_barrier(0);                                    \
    }
#define PHASE_O(XON)                                                          \
    {                                                                         \
        CL_H1(aO0, aO1, aO2, aO3, bn0, bn1, bn2, bn3)                         \
        __builtin_amdgcn_sched_barrier(0);                                    \
        LOADB(bc0, bc1, bc2, bc3, bc4, bc5, bc6, XON)                         \
        __builtin_amdgcn_sched_barrier(0);                                    \
        CL_H2(aO0, aO1, aO2, aO3, bn4, bn5, bn6)                              \
        __builtin_amdgcn_sched_barrier(0);                                    \
        GLOADA(aO0, aO1, aO2, aO3)                                            \
        __builtin_amdgcn_sched_barrier(0);                                    \
    }

// Implicit-GEMM conv: r16 staging/epilogue + A via depth-2 register ring
// (no A LDS traffic, no DMA). 224 blocks (XCD-swizzled), 512 thr = 8 waves.
__global__ __launch_bounds__(512, 2) void conv_kernel(
    const float* __restrict__ x, const __hip_bfloat16* __restrict__ wrt,
    const float* __restrict__ xg, const float* __restrict__ w1,
    const float* __restrict__ b1, float* __restrict__ out) {
    __shared__ __align__(16) char SMEM[116736];
    char* Xs = SMEM;                               // 92160: x-slab (K-loop live)
    float* hsm = (float*)(SMEM + 114688);          // 2048: h (live whole kernel)
    float* Xf = (float*)SMEM;                      // epilogue: 114688 B (Xs dead)
    const int bid = blockIdx.x;
    const int v = (bid & 7) * 28 + (bid >> 3);     // bijective XCD swizzle (224 % 8 == 0)
    const int b = v / 7;
    const int nt = v - b * 7;
    const int tid = threadIdx.x;
    const int lane = tid & 63;
    const int wv = tid >> 6;
    const int mw = wv & 3;
    const int kw2 = wv >> 2;
    const int kcol = lane & 15;
    const int klo = lane >> 4;

    const char* pA = (const char*)wrt + (kw2 * 4 + mw) * 4096 + lane * 16;

    // h[j] = sigmoid(xg[b].w1[j] + b1[j])
    {
        float s = b1[tid];
        const float* g = xg + b * 16;
        const float* w = w1 + tid * 16;
#pragma unroll
        for (int c = 0; c < 16; ++c) s += g[c] * w[c];
        hsm[tid] = 1.0f / (1.0f + expf(-s));
    }

    // ---- x-slab staging from x (fp32 NCHW): quad-channel b64 swizzled writes.
    // Position sp, channel ch at sp*512 + ((ch>>3 ^ key(sp))<<4) + (ch&7)*2,
    // key(sp) = (q+4r)&7 (r16-verified layout).
    {
        const bf16x8 z = (bf16x8){0, 0, 0, 0, 0, 0, 0, 0};
        for (int e = tid; e < 6 * 2 * 32; e += 512) {       // pad cols 0/29
            int w = e & 31;
            int t2 = e >> 5;
            int row = t2 >> 1;
            int col = (t2 & 1) ? 29 : 0;
            *(bf16x8*)(Xs + (row * 30 + col) * 512 + w * 16) = z;
        }
        if (nt == 0) {                                       // pad top row
            for (int e = tid; e < 30 * 32; e += 512)
                *(bf16x8*)(Xs + (e >> 5) * 512 + (e & 31) * 16) = z;
        }
        if (nt == 6) {                                       // pad bottom row
            for (int e = tid; e < 30 * 32; e += 512)
                *(bf16x8*)(Xs + (150 + (e >> 5)) * 512 + (e & 31) * 16) = z;
        }
        const int p0 = nt * 4 - 1;
        const float* xb = x + (size_t)b * 256 * 784;
        for (int c = tid; c < 2688; c += 512) {              // 6 rows x 64 ch-quads x 7 c4
            int c4 = c % 7;
            int t2 = c / 7;
            int chq = t2 & 63;
            int row = t2 >> 6;
            int p = p0 + row;
            if (p >= 0 && p < 28) {
                const float* s0 = xb + ((size_t)(chq * 4) * 28 + p) * 28 + 4 * c4;
                f32x4 v0 = *(const f32x4*)(s0);
                f32x4 v1 = *(const f32x4*)(s0 + 784);
                f32x4 v2 = *(const f32x4*)(s0 + 1568);
                f32x4 v3 = *(const f32x4*)(s0 + 2352);
                int w = chq >> 1;
                int qoff = (chq & 1) * 8;
                int spb = row * 30 + 4 * c4 + 1;
#pragma unroll
                for (int k = 0; k < 4; ++k) {
                    int key = (4 * c4 + 1 + k + 4 * row) & 7;
                    union { bf16x4 vv; __hip_bfloat16 e[4]; } pk;
                    pk.e[0] = __float2bfloat16(v0[k]);
                    pk.e[1] = __float2bfloat16(v1[k]);
                    pk.e[2] = __float2bfloat16(v2[k]);
                    pk.e[3] = __float2bfloat16(v3[k]);
                    *(bf16x4*)(Xs + (spb + k) * 512 + (((w ^ key) << 4) | qoff)) = pk.vv;
                }
            }
        }
    }
    __syncthreads();   // Xs + hsm ready

    unsigned u[7], kk[7];
#pragma unroll
    for (int nf = 0; nf < 7; ++nf) {
        int n = nf * 16 + kcol;
        int r0 = n / 28;
        int q0 = n - r0 * 28;
        u[nf] = (unsigned)((r0 * 30 + q0) * 512 + (klo << 4));
        kk[nf] = (unsigned)(q0 + 4 * r0);
    }
    const unsigned xo0 = (unsigned)((kw2 * 4 + 0) << 6);
    const unsigned xo1 = (unsigned)((kw2 * 4 + 1) << 6);
    const unsigned xo2 = (unsigned)((kw2 * 4 + 2) << 6);
    const unsigned xo3 = (unsigned)((kw2 * 4 + 3) << 6);

    f32x4 acc[4][7];
#pragma unroll
    for (int mf = 0; mf < 4; ++mf)
#pragma unroll
        for (int nf = 0; nf < 7; ++nf) acc[mf][nf] = (f32x4){0.f, 0.f, 0.f, 0.f};

    bf16x8 aE0, aE1, aE2, aE3, aO0, aO1, aO2, aO3;
    bf16x8 bc0, bc1, bc2, bc3, bc4, bc5, bc6;
    bf16x8 bn0, bn1, bn2, bn3, bn4, bn5, bn6;

    // prologue: A(0) -> set E, A(1) -> set O, B(0) -> set c
    GLOADA(aE0, aE1, aE2, aE3)
    GLOADA(aO0, aO1, aO2, aO3)
    LOADB(bc0, bc1, bc2, bc3, bc4, bc5, bc6, xo0)

    for (int tap = 0; tap < 9; ++tap) {
        PHASE_E(xo1)                      // consume (E, bc); load bn=B(ic1), A(s+2)->E
        PHASE_O(xo2)                      // consume (O, bn); load bc=B(ic2), A->O
        PHASE_E(xo3)
        if (tap < 8) {                    // advance geometry before next-tap B load
            const int cross = (tap == 2 || tap == 5);
            const unsigned da = cross ? 28u * 512u : 512u;
            const unsigned dk = cross ? 2u : 1u;
#pragma unroll
            for (int nf = 0; nf < 7; ++nf) { u[nf] += da; kk[nf] += dk; }
        }
        PHASE_O(xo0)                      // loads bc=B(tap+1,ic0) (tap8: harmless reread)
    }
    // tail GLOADA reads ~65KB past wrt into the (allocated) ws region -- never consumed.

    // ---- epilogue, single round: Xf over Xs (dead); hsm at 114688 untouched.
    __syncthreads();
    if (kw2 == 1) {
#pragma unroll
        for (int mf = 0; mf < 4; ++mf)
#pragma unroll
            for (int nf = 0; nf < 7; ++nf)
#pragma unroll
                for (int rr = 0; rr < 4; ++rr) {
                    int o = mw * 64 + mf * 16 + klo * 4 + rr;
                    int idx = (((mw * 4 + mf) * 7 + nf) * 4 + rr) * 64 + lane;
                    Xf[idx] = hsm[2 * o + 1] * acc[mf][nf][rr];
                }
    }
    __syncthreads();
    if (kw2 == 0) {
#pragma unroll
        for (int mf = 0; mf < 4; ++mf)
#pragma unroll
            for (int nf = 0; nf < 7; ++nf)
#pragma unroll
                for (int rr = 0; rr < 4; ++rr) {
                    int o = mw * 64 + mf * 16 + klo * 4 + rr;
                    int idx = (((mw * 4 + mf) * 7 + nf) * 4 + rr) * 64 + lane;
                    float y = hsm[2 * o] * acc[mf][nf][rr] + Xf[idx];
                    out[((size_t)b * NO + o) * 784 + nt * 112 + nf * 16 + kcol] = y;
                }
    }
}

extern "C" void kernel_launch(void* const* d_in, const int* in_sizes, int n_in,
                              void* d_out, int out_size, void* d_ws, size_t ws_size,
                              hipStream_t stream) {
    const float* x = (const float*)d_in[0];
    const float* xg = (const float*)d_in[1];
    const float* w1 = (const float*)d_in[2];
    const float* b1 = (const float*)d_in[3];
    const float* w2 = (const float*)d_in[4];
    float* out = (float*)d_out;

    char* ws = (char*)d_ws;
    __hip_bfloat16* wrt = (__hip_bfloat16*)ws;   // 1,179,648 B (+ tail-overrun slack in ws)

    prep_kernel<<<288, 256, 0, stream>>>(w2, wrt);
    conv_kernel<<<224, 512, 0, stream>>>(x, wrt, xg, w1, b1, out);
}